// Round 13
// baseline (152.312 us; speedup 1.0000x reference)
//
#include <hip/hip_runtime.h>
#include <stdint.h>
#include <math.h>

namespace {

constexpr int kB  = 2;
constexpr int kS  = 2048;
constexpr int kD  = 1024;
constexpr int kH  = 16;
constexpr int kHD = 64;
constexpr int kBS = kB * kS;   // 4096
constexpr int kD3 = 3 * kD;    // 3072

typedef __attribute__((ext_vector_type(8)))  __bf16 bf16x8;
typedef __attribute__((ext_vector_type(4)))  float  f32x4;
typedef __attribute__((ext_vector_type(16))) float  f32x16;

__device__ __forceinline__ unsigned short f2bf(float f) {
  unsigned u = __float_as_uint(f);
  u += 0x7fffu + ((u >> 16) & 1u);          // RNE
  return (unsigned short)(u >> 16);
}
__device__ __forceinline__ float bf2f(unsigned short b) {
  return __uint_as_float(((unsigned)b) << 16);
}
__device__ __forceinline__ unsigned pk2(float lo, float hi) {
  return (unsigned)f2bf(lo) | ((unsigned)f2bf(hi) << 16);
}
__device__ __forceinline__ unsigned cvtpk(float lo, float hi) {
  unsigned r;
  asm("v_cvt_pk_bf16_f32 %0, %1, %2" : "=v"(r) : "v"(lo), "v"(hi));
  return r;
}
__device__ __forceinline__ float max3f(float a, float b, float c) {
  float d;
  asm("v_max3_f32 %0, %1, %2, %3" : "=v"(d) : "v"(a), "v"(b), "v"(c));
  return d;
}
__device__ __forceinline__ void gload_lds16(const void* g, void* l) {
  __builtin_amdgcn_global_load_lds((const __attribute__((address_space(1))) void*)g,
                                   (__attribute__((address_space(3))) void*)l, 16, 0, 0);
}

// ---------------- fused prep: f32->bf16 (q, W_all, W_out) + merged-mask pack ----------------
// blocks 0..8191: bf16 convert; blocks 8192..9215: mask pack (self-detecting dtype).
__global__ __launch_bounds__(256) void prep_kernel(const float* __restrict__ q,
                                                   const float* __restrict__ Wa,
                                                   const float* __restrict__ Wo,
                                                   const int* __restrict__ attn,
                                                   const int* __restrict__ kv,
                                                   unsigned short* __restrict__ qb,
                                                   unsigned short* __restrict__ wab,
                                                   unsigned short* __restrict__ wob,
                                                   unsigned* __restrict__ mout) {
  int bx = blockIdx.x;
  if (bx < 8192) {
    const float* src; unsigned short* dst; int base;
    if (bx < 4096)      { src = q;  dst = qb;  base = 0; }     // 4,194,304 elems
    else if (bx < 7168) { src = Wa; dst = wab; base = 4096; }  // 3,145,728
    else                { src = Wo; dst = wob; base = 7168; }  // 1,048,576
    int i = (bx - base) * 256 + threadIdx.x;
    float4 v = reinterpret_cast<const float4*>(src)[i];
    uint2 o;
    o.x = pk2(v.x, v.y);
    o.y = pk2(v.z, v.w);
    reinterpret_cast<uint2*>(dst)[i] = o;
    return;
  }
  // ---- mask pack: flag=0 -> 32-bit elems (int32 0/1 or f32 0.0/1.0); flag=1 -> bytes ----
  __shared__ int sflag;
  {
    unsigned v = ((const unsigned*)attn)[threadIdx.x];
    bool isbad = (v != 0u) && (v != 1u) && (v != 0x3f800000u);
    unsigned long long bal = __ballot(isbad);
    if (threadIdx.x == 0) sflag = 0;
    __syncthreads();
    if ((threadIdx.x & 63) == 0 && bal != 0ull) sflag = 1;
    __syncthreads();
  }
  const int flag = sflag;

  int idx = (bx - 8192) * 256 + threadIdx.x;   // (b*kS + q)*64 + w
  int w = idx & 63;
  int qq = (idx >> 6) & (kS - 1);
  int b = idx >> 17;
  unsigned m = 0;
  if (flag == 0) {
    const int* ap = attn + ((size_t)(b * kS + qq)) * kS + w * 32;
    const int* kp = kv + b * kS + w * 32;
#pragma unroll
    for (int i = 0; i < 32; i++)
      if ((ap[i] != 0) & (kp[i] != 0)) m |= (1u << i);
  } else {
    const unsigned char* ap = (const unsigned char*)attn + ((size_t)(b * kS + qq)) * kS + w * 32;
    const unsigned char* kp = (const unsigned char*)kv + b * kS + w * 32;
#pragma unroll
    for (int i = 0; i < 32; i++)
      if ((ap[i] != 0) & (kp[i] != 0)) m |= (1u << i);
  }
  mout[idx] = m;
}

// ---------------- GEMM: C[M,N] = A[M,K] @ Bt[N,K]^T (+bias), bf16 in, f32 acc ----------------
// 128x128 tile, BK=64, 256 thr (4 waves, 2x2 of 64x64), 16x16x32 MFMA x2 k-halves.
// Swizzle: phys slot = logical ^ (row&7), via pre-swizzled global source.
// Linear x-major block mapping. NOTE (R12 lesson): do NOT "XCD-chunk" this grid --
// with linear mapping the CO-RESIDENT set per XCD (4 A-panels + 8 B-panels = 3MB)
// already fits L2; chunking forces 5MB resident and thrashes. Temporal working set,
// not full-grid footprint, is what must fit.
template <int OUT_BF16, int HAS_BIAS>
__global__ __launch_bounds__(256, 2) void gemm_kernel(const unsigned short* __restrict__ A,
                                                      const unsigned short* __restrict__ Bt,
                                                      void* __restrict__ Cv,
                                                      const float* __restrict__ bias,
                                                      int M, int N, int K) {
  __shared__ alignas(16) unsigned short As[128 * 64];
  __shared__ alignas(16) unsigned short Bs[128 * 64];
  const int tid  = threadIdx.x;
  const int lane = tid & 63;
  const int wave = tid >> 6;
  const int wr = wave >> 1, wc = wave & 1;
  const int bm = blockIdx.x * 128;
  const int bn = blockIdx.y * 128;

  f32x4 acc[4][4] = {};

  const int srow  = tid >> 3;                   // 0..31
  const int sslot = (tid & 7) ^ (srow & 7);
  const unsigned short* ga = A + (size_t)(bm + srow) * K + sslot * 8;
  const unsigned short* gb = Bt + (size_t)(bn + srow) * K + sslot * 8;
  char* lA = (char*)As + wave * 1024;           // linear dest: wave base + lane*16B
  char* lB = (char*)Bs + wave * 1024;

  for (int kk = 0; kk < K; kk += 64) {
    __syncthreads();
#pragma unroll
    for (int rb = 0; rb < 4; rb++) {
      gload_lds16(ga + (size_t)(32 * rb) * K, lA + rb * 4096);
      gload_lds16(gb + (size_t)(32 * rb) * K, lB + rb * 4096);
    }
    ga += 64; gb += 64;
    __syncthreads();

    bf16x8 af[4][2], bfr[4][2];
#pragma unroll
    for (int i = 0; i < 4; i++) {
#pragma unroll
      for (int t = 0; t < 2; t++) {
        int rA = wr * 64 + i * 16 + (lane & 15);
        int jA = (t * 4 + (lane >> 4)) ^ (rA & 7);
        af[i][t] = *(const bf16x8*)(As + rA * 64 + jA * 8);
        int rB = wc * 64 + i * 16 + (lane & 15);
        int jB = (t * 4 + (lane >> 4)) ^ (rB & 7);
        bfr[i][t] = *(const bf16x8*)(Bs + rB * 64 + jB * 8);
      }
    }
#pragma unroll
    for (int mi = 0; mi < 4; mi++)
#pragma unroll
      for (int ni = 0; ni < 4; ni++) {
        acc[mi][ni] = __builtin_amdgcn_mfma_f32_16x16x32_bf16(af[mi][0], bfr[ni][0], acc[mi][ni], 0, 0, 0);
        acc[mi][ni] = __builtin_amdgcn_mfma_f32_16x16x32_bf16(af[mi][1], bfr[ni][1], acc[mi][ni], 0, 0, 0);
      }
  }

  const int r0 = bm + wr * 64 + (lane >> 4) * 4;
  const int c0 = bn + wc * 64 + (lane & 15);
#pragma unroll
  for (int ni = 0; ni < 4; ni++) {
    int c = c0 + ni * 16;
    float bv = HAS_BIAS ? bias[c] : 0.0f;
#pragma unroll
    for (int mi = 0; mi < 4; mi++) {
#pragma unroll
      for (int j = 0; j < 4; j++) {
        int r = r0 + mi * 16 + j;
        float v = acc[mi][ni][j] + bv;
        if (OUT_BF16) ((unsigned short*)Cv)[(size_t)r * N + c] = f2bf(v);
        else          ((float*)Cv)[(size_t)r * N + c] = v;
      }
    }
  }
}

// ---------------- flash attention: R8 champion, verbatim ----------------
// software-pipelined, 512 thr, 1 barrier/tile. Grid (bh=32, qchunk=8): XCD = bh%8.
// Pipeline: QK^T(t+1) first; K(t+2) gload + V(t+2) loads before VALU phase; V write after PV.
// K double-buffered, V triple-buffered, scores ping-pong via 2x-unrolled body.
// ~164 unified regs/wave -> (512,2); >=4 waves/SIMD bounds spill catastrophically (R4/R6/R9).
__global__ __launch_bounds__(512, 2) void attn_kernel(const unsigned short* __restrict__ qkv,   // [4096][3072]
                                                      const unsigned* __restrict__ maskp,       // [B][S][64]
                                                      unsigned short* __restrict__ aout) {      // [4096][1024]
  __shared__ alignas(16) unsigned short Ks[2][64 * 64];   // [key][hd], 16B slot ^= key&7
  __shared__ alignas(16) unsigned short Vt[3][64 * 64];   // [hd][key], 16B slot ^= hd&7
  const int tid  = threadIdx.x;
  const int lane = tid & 63;
  const int wave = tid >> 6;
  const int half = lane >> 5;
  const int l31  = lane & 31;
  const int b = blockIdx.x >> 4;
  const int h = blockIdx.x & 15;
  const int qrow = blockIdx.y * 256 + wave * 32 + l31;
  const float NEGINF = -__builtin_inff();
  const float K2 = 1.4426950408889634f;     // log2(e)

  // Q fragments (B-operand), pre-scaled by 1/sqrt(HD)=0.125 (exact in bf16)
  bf16x8 qf[4];
  {
    const unsigned short* qp = qkv + (size_t)(b * kS + qrow) * kD3 + h * kHD + half * 8;
#pragma unroll
    for (int i = 0; i < 4; i++) {
      uint4 u = *(const uint4*)(qp + i * 16);
      unsigned w[4] = {u.x, u.y, u.z, u.w};
      union { unsigned u[4]; bf16x8 v; } o;
#pragma unroll
      for (int j = 0; j < 4; j++) {
        float lo = bf2f((unsigned short)(w[j] & 0xffffu)) * 0.125f;
        float hi = bf2f((unsigned short)(w[j] >> 16)) * 0.125f;
        o.u[j] = pk2(lo, hi);
      }
      qf[i] = o.v;
    }
  }

  f32x16 ot0 = {}, ot1 = {};                 // O^T acc: hd 0-31 / 32-63, col=qrow
  float mrun = NEGINF, lrun = 0.f, m2 = 0.f; // m2 = mrun*log2e
  const unsigned* mp = maskp + ((size_t)(b * kS) + qrow) * 64;

  // K staging: 16B chunk: row=tid>>3, dest slot=tid&7; source pre-swizzled
  const int krow  = tid >> 3;
  const int kslot = (tid & 7) ^ (krow & 7);
  const unsigned short* gk = qkv + (size_t)(b * kS + krow) * kD3 + kD + h * kHD + kslot * 8;

  // V staging (register transpose, b64 writes)
  const int vp = tid >> 4;          // hd pair {2vp, 2vp+1}
  const int vo = (tid >> 1) & 7;    // key octet
  const int vh = tid & 1;           // half-octet (4 keys)
  const unsigned short* gv = qkv + (size_t)(b * kS + 8 * vo + 4 * vh) * kD3 + 2 * kD + h * kHD + 2 * vp;
  const int vwo_lo = (2 * vp) * 128 + ((vo ^ ((2 * vp) & 7)) << 4) + vh * 8;           // bytes
  const int vwo_hi = (2 * vp + 1) * 128 + ((vo ^ ((2 * vp + 1) & 7)) << 4) + vh * 8;

  const size_t tstride = (size_t)64 * kD3;   // one 64-key tile

  // ---------------- prologue: stage K(0),K(1),V(0),V(1); QK^T(0) ----------------
  gload_lds16(gk, (char*)Ks[0] + tid * 16);
  gload_lds16(gk + tstride, (char*)Ks[1] + tid * 16);
  {
    unsigned p0 = *(const unsigned*)(gv);
    unsigned p1 = *(const unsigned*)(gv + kD3);
    unsigned p2 = *(const unsigned*)(gv + 2 * kD3);
    unsigned p3 = *(const unsigned*)(gv + 3 * kD3);
    char* vb = (char*)Vt[0];
    uint2 wlo, whi;
    wlo.x = __builtin_amdgcn_perm(p1, p0, 0x05040100u);
    wlo.y = __builtin_amdgcn_perm(p3, p2, 0x05040100u);
    whi.x = __builtin_amdgcn_perm(p1, p0, 0x07060302u);
    whi.y = __builtin_amdgcn_perm(p3, p2, 0x07060302u);
    *(uint2*)(vb + vwo_lo) = wlo;
    *(uint2*)(vb + vwo_hi) = whi;
  }
  unsigned v0 = *(const unsigned*)(gv + tstride);
  unsigned v1 = *(const unsigned*)(gv + tstride + kD3);
  unsigned v2 = *(const unsigned*)(gv + tstride + 2 * kD3);
  unsigned v3 = *(const unsigned*)(gv + tstride + 3 * kD3);
  uint2 mw = *(const uint2*)(mp);
  __syncthreads();                          // K0,K1 in LDS; V0 visible

  f32x16 sA0 = {}, sA1 = {}, sB0 = {}, sB1 = {};
  {
    const unsigned short* ksb = Ks[0];
    __builtin_amdgcn_s_setprio(1);
#pragma unroll
    for (int ii = 0; ii < 4; ii++) {
      int slot = (ii * 2 + half) ^ (l31 & 7);
      bf16x8 ka0 = *(const bf16x8*)(ksb + l31 * 64 + slot * 8);
      bf16x8 ka1 = *(const bf16x8*)(ksb + (l31 + 32) * 64 + slot * 8);
      sA0 = __builtin_amdgcn_mfma_f32_32x32x16_bf16(ka0, qf[ii], sA0, 0, 0, 0);
      sA1 = __builtin_amdgcn_mfma_f32_32x32x16_bf16(ka1, qf[ii], sA1, 0, 0, 0);
    }
    __builtin_amdgcn_s_setprio(0);
  }
  {
    char* vb = (char*)Vt[1];
    uint2 wlo, whi;
    wlo.x = __builtin_amdgcn_perm(v1, v0, 0x05040100u);
    wlo.y = __builtin_amdgcn_perm(v3, v2, 0x05040100u);
    whi.x = __builtin_amdgcn_perm(v1, v0, 0x07060302u);
    whi.y = __builtin_amdgcn_perm(v3, v2, 0x07060302u);
    *(uint2*)(vb + vwo_lo) = wlo;
    *(uint2*)(vb + vwo_hi) = whi;
  }
  __syncthreads();                          // QK^T(0) reads done (Ks[0] reusable); V1 visible

  int vrd_off = 0;                          // (t%3)*8192 bytes
  int vwr_off = 16384;                      // ((t+2)%3)*8192 bytes

  // body(t): QK^T(t+1)->NXT from KNXT; gload K(t+2)->KDST; softmax+PV(t) on CUR
#define BODY(T, CUR0, CUR1, NXT0, NXT1, KNXT, KDST)                                         \
  {                                                                                         \
    const int t_ = (T);                                                                     \
    if (t_ < 31) {                                                                          \
      const unsigned short* ksb = (KNXT);                                                   \
      NXT0 = (f32x16){}; NXT1 = (f32x16){};                                                 \
      __builtin_amdgcn_s_setprio(1);                                                        \
      _Pragma("unroll")                                                                     \
      for (int ii = 0; ii < 4; ii++) {                                                      \
        int slot = (ii * 2 + half) ^ (l31 & 7);                                             \
        bf16x8 ka0 = *(const bf16x8*)(ksb + l31 * 64 + slot * 8);                           \
        bf16x8 ka1 = *(const bf16x8*)(ksb + (l31 + 32) * 64 + slot * 8);                    \
        NXT0 = __builtin_amdgcn_mfma_f32_32x32x16_bf16(ka0, qf[ii], NXT0, 0, 0, 0);         \
        NXT1 = __builtin_amdgcn_mfma_f32_32x32x16_bf16(ka1, qf[ii], NXT1, 0, 0, 0);         \
      }                                                                                     \
      __builtin_amdgcn_s_setprio(0);                                                        \
    }                                                                                       \
    __builtin_amdgcn_sched_barrier(0);                                                      \
    uint2 mwn = mw;                                                                         \
    if (t_ < 31) mwn = *(const uint2*)(mp + 2 * (t_ + 1));                                  \
    if (t_ < 30) {                                                                          \
      gload_lds16(gk + (size_t)(t_ + 2) * tstride, (KDST) + tid * 16);                      \
      const unsigned short* gvn = gv + (size_t)(t_ + 2) * tstride;                          \
      v0 = *(const unsigned*)(gvn);                                                         \
      v1 = *(const unsigned*)(gvn + kD3);                                                   \
      v2 = *(const unsigned*)(gvn + 2 * kD3);                                               \
      v3 = *(const unsigned*)(gvn + 3 * kD3);                                               \
    }                                                                                       \
    const unsigned mx = mw.x >> (4 * half);                                                 \
    const unsigned my = mw.y >> (4 * half);                                                 \
    float pm = NEGINF;                                                                      \
    _Pragma("unroll")                                                                       \
    for (int r = 0; r < 16; r++) pm = max3f(CUR0[r], CUR1[r], pm);                          \
    pm = fmaxf(pm, __shfl_xor(pm, 32));                                                     \
    if (__any(pm > mrun + 8.0f)) {                                                          \
      float mn = fmaxf(mrun, pm);                                                           \
      float m2n = mn * K2;                                                                  \
      float sc = __builtin_amdgcn_exp2f(fmaf(mrun, K2, -m2n));                              \
      m2 = m2n; mrun = mn; lrun *= sc;                                                      \
      _Pragma("unroll")                                                                     \
      for (int r = 0; r < 16; r++) { ot0[r] *= sc; ot1[r] *= sc; }                          \
    }                                                                                       \
    float ls0 = 0.f, ls1 = 0.f;                                                             \
    _Pragma("unroll")                                                                       \
    for (int r = 0; r < 16; r++) {                                                          \
      const int kb = (r & 3) + 8 * (r >> 2);                                                \
      float p0 = __builtin_amdgcn_exp2f(fmaf(CUR0[r], K2, -m2));                            \
      float p1 = __builtin_amdgcn_exp2f(fmaf(CUR1[r], K2, -m2));                            \
      unsigned z0 = (unsigned)__builtin_amdgcn_sbfe(mx, kb, 1);                             \
      unsigned z1 = (unsigned)__builtin_amdgcn_sbfe(my, kb, 1);                             \
      p0 = __uint_as_float(__float_as_uint(p0) & z0);                                       \
      p1 = __uint_as_float(__float_as_uint(p1) & z1);                                       \
      CUR0[r] = p0; CUR1[r] = p1;                                                           \
      ls0 += p0; ls1 += p1;                                                                 \
    }                                                                                       \
    float ls = ls0 + ls1;                                                                   \
    ls += __shfl_xor(ls, 32);                                                               \
    lrun += ls;                                                                             \
    const char* vtb = (const char*)Vt[0] + vrd_off;                                         \
    _Pragma("unroll")                                                                       \
    for (int gg = 0; gg < 2; gg++) {                                                        \
      unsigned w8[8];                                                                       \
      _Pragma("unroll")                                                                     \
      for (int j = 0; j < 8; j++)                                                           \
        w8[j] = gg ? cvtpk(CUR1[2 * j], CUR1[2 * j + 1])                                    \
                   : cvtpk(CUR0[2 * j], CUR0[2 * j + 1]);                                   \
      _Pragma("unroll")                                                                     \
      for (int cc = 0; cc < 2; cc++) {                                                      \
        unsigned u0 = w8[4 * cc],     u2 = w8[4 * cc + 2];                                  \
        unsigned u1 = w8[4 * cc + 1], u3 = w8[4 * cc + 3];                                  \
        asm("v_permlane32_swap_b32 %0, %1" : "+v"(u0), "+v"(u2));                           \
        asm("v_permlane32_swap_b32 %0, %1" : "+v"(u1), "+v"(u3));                           \
        union { unsigned u[4]; bf16x8 v; } pb;                                              \
        pb.u[0] = u0; pb.u[1] = u1; pb.u[2] = u2; pb.u[3] = u3;                             \
        int c = gg * 2 + cc;                                                                \
        int kslotc = (c * 2 + half) ^ (l31 & 7);                                            \
        __builtin_amdgcn_s_setprio(1);                                                      \
        {                                                                                   \
          bf16x8 va0 = *(const bf16x8*)(vtb + l31 * 128 + kslotc * 16);                     \
          bf16x8 va1 = *(const bf16x8*)(vtb + (l31 + 32) * 128 + kslotc * 16);              \
          ot0 = __builtin_amdgcn_mfma_f32_32x32x16_bf16(va0, pb.v, ot0, 0, 0, 0);           \
          ot1 = __builtin_amdgcn_mfma_f32_32x32x16_bf16(va1, pb.v, ot1, 0, 0, 0);           \
        }                                                                                   \
        __builtin_amdgcn_s_setprio(0);                                                      \
      }                                                                                     \
    }                                                                                       \
    if (t_ < 30) {                                                                          \
      char* vb = (char*)Vt[0] + vwr_off;                                                    \
      uint2 wlo, whi;                                                                       \
      wlo.x = __builtin_amdgcn_perm(v1, v0, 0x05040100u);                                   \
      wlo.y = __builtin_amdgcn_perm(v3, v2, 0x05040100u);                                   \
      whi.x = __builtin_amdgcn_perm(v1, v0, 0x07060302u);                                   \
      whi.y = __builtin_amdgcn_perm(v3, v2, 0x07060302u);                                   \
      *(uint2*)(vb + vwo_lo) = wlo;                                                         \
      *(uint2*)(vb + vwo_hi) = whi;                                                         \
    }                                                                                       \
    mw = mwn;                                                                               \
    vrd_off = (vrd_off == 16384) ? 0 : vrd_off + 8192;                                      \
    vwr_off = (vwr_off == 16384) ? 0 : vwr_off + 8192;                                      \
    __syncthreads();                                                                        \
  }

  for (int tp = 0; tp < 16; ++tp) {
    const int te = 2 * tp;
    BODY(te,     sA0, sA1, sB0, sB1, Ks[1], (char*)Ks[0]);
    BODY(te + 1, sB0, sB1, sA0, sA1, Ks[0], (char*)Ks[1]);
  }
#undef BODY

  // ---- normalize + write a_out bf16 (fully-masked row -> 0) ----
  float rl = (lrun > 0.f) ? (1.f / lrun) : 0.f;
  unsigned short* op = aout + (size_t)(b * kS + qrow) * kD + h * kHD;
#pragma unroll
  for (int hh = 0; hh < 2; hh++) {
#pragma unroll
    for (int qd = 0; qd < 4; qd++) {
      float x0 = (hh ? ot1[4 * qd]     : ot0[4 * qd])     * rl;
      float x1 = (hh ? ot1[4 * qd + 1] : ot0[4 * qd + 1]) * rl;
      float x2 = (hh ? ot1[4 * qd + 2] : ot0[4 * qd + 2]) * rl;
      float x3 = (hh ? ot1[4 * qd + 3] : ot0[4 * qd + 3]) * rl;
      uint2 o;
      o.x = pk2(x0, x1);
      o.y = pk2(x2, x3);
      *(uint2*)(op + hh * 32 + qd * 8 + half * 4) = o;
    }
  }
}

}  // namespace

extern "C" void kernel_launch(void* const* d_in, const int* in_sizes, int n_in,
                              void* d_out, int out_size, void* d_ws, size_t ws_size,
                              hipStream_t stream) {
  (void)in_sizes; (void)n_in; (void)out_size; (void)ws_size;
  const float* q     = (const float*)d_in[0];
  const int*   kvm   = (const int*)d_in[1];
  const int*   am    = (const int*)d_in[2];
  const float* W_all = (const float*)d_in[3];
  const float* W_out = (const float*)d_in[4];
  const float* b_out = (const float*)d_in[5];

  char* ws = (char*)d_ws;
  unsigned short* qkv  = (unsigned short*)(ws);                    // 25,165,824 B
  unsigned short* qbf  = (unsigned short*)(ws + 25165824);         //  8,388,608 B (reused as aout)
  unsigned short* aout = qbf;
  unsigned short* wabf = (unsigned short*)(ws + 33554432);         //  6,291,456 B
  unsigned short* wobf = (unsigned short*)(ws + 39845888);         //  2,097,152 B
  unsigned*       mskp = (unsigned*)(ws + 41943040);               //  1,048,576 B

  // prep (blocks 0-8191: bf16 cvt) + maskpack (blocks 8192-9215), one launch
  prep_kernel<<<9216, 256, 0, stream>>>(q, W_all, W_out, am, kvm, qbf, wabf, wobf, mskp);
  // qkv[4096,3072] = q_bf @ W_all^T ; linear x-major grid (co-resident set fits L2)
  gemm_kernel<1, 0><<<dim3(kBS / 128, kD3 / 128), 256, 0, stream>>>(qbf, wabf, qkv, nullptr, kBS, kD3, kD);
  // a_out[4096,1024] (bf16); grid x=bh (XCD-local K/V), y=q-chunk
  attn_kernel<<<dim3(kB * kH, kS / 256), 512, 0, stream>>>(qkv, mskp, aout);
  // out[4096,1024] = a_out @ W_out^T + b_out (f32)
  gemm_kernel<0, 1><<<dim3(kBS / 128, kD / 128), 256, 0, stream>>>(aout, wobf, d_out, b_out, kBS, kD, kD);
}

// Round 14
// 145.675 us; speedup vs baseline: 1.0456x; 1.0456x over previous
//
#include <hip/hip_runtime.h>
#include <stdint.h>
#include <math.h>

namespace {

constexpr int kB  = 2;
constexpr int kS  = 2048;
constexpr int kD  = 1024;
constexpr int kH  = 16;
constexpr int kHD = 64;
constexpr int kBS = kB * kS;   // 4096
constexpr int kD3 = 3 * kD;    // 3072

typedef __attribute__((ext_vector_type(8)))  __bf16 bf16x8;
typedef __attribute__((ext_vector_type(4)))  float  f32x4;
typedef __attribute__((ext_vector_type(16))) float  f32x16;

__device__ __forceinline__ unsigned short f2bf(float f) {
  unsigned u = __float_as_uint(f);
  u += 0x7fffu + ((u >> 16) & 1u);          // RNE
  return (unsigned short)(u >> 16);
}
__device__ __forceinline__ float bf2f(unsigned short b) {
  return __uint_as_float(((unsigned)b) << 16);
}
__device__ __forceinline__ unsigned pk2(float lo, float hi) {
  return (unsigned)f2bf(lo) | ((unsigned)f2bf(hi) << 16);
}
__device__ __forceinline__ unsigned cvtpk(float lo, float hi) {
  unsigned r;
  asm("v_cvt_pk_bf16_f32 %0, %1, %2" : "=v"(r) : "v"(lo), "v"(hi));
  return r;
}
__device__ __forceinline__ float max3f(float a, float b, float c) {
  float d;
  asm("v_max3_f32 %0, %1, %2, %3" : "=v"(d) : "v"(a), "v"(b), "v"(c));
  return d;
}
__device__ __forceinline__ void gload_lds16(const void* g, void* l) {
  __builtin_amdgcn_global_load_lds((const __attribute__((address_space(1))) void*)g,
                                   (__attribute__((address_space(3))) void*)l, 16, 0, 0);
}

// ---------------- f32 -> bf16 (4 elems/thread); fused over q, W_all, W_out ----------------
// (R13 lesson: do NOT fuse maskpack into this kernel -- fusing cost ~5us, likely because the
//  fatter maskpack branch degrades the streaming blocks' codegen/occupancy.)
__global__ __launch_bounds__(256) void prep_kernel(const float* __restrict__ q,
                                                   const float* __restrict__ Wa,
                                                   const float* __restrict__ Wo,
                                                   unsigned short* __restrict__ qb,
                                                   unsigned short* __restrict__ wab,
                                                   unsigned short* __restrict__ wob) {
  int bx = blockIdx.x;
  const float* src; unsigned short* dst; int base;
  if (bx < 4096)      { src = q;  dst = qb;  base = 0; }     // 4,194,304 elems
  else if (bx < 7168) { src = Wa; dst = wab; base = 4096; }  // 3,145,728
  else                { src = Wo; dst = wob; base = 7168; }  // 1,048,576
  int i = (bx - base) * 256 + threadIdx.x;
  float4 v = reinterpret_cast<const float4*>(src)[i];
  uint2 o;
  o.x = pk2(v.x, v.y);
  o.y = pk2(v.z, v.w);
  reinterpret_cast<uint2*>(dst)[i] = o;
}

// ---------------- packed merged mask (self-detecting dtype, uint4-vectorized) ----------------
// flag=0: 32-bit elems (int32 0/1 or f32 0.0/1.0 -> "!=0" works); flag=1: byte bools.
// Every block samples attn[0..255] (same data, L2-broadcast) -> consistent answer.
__global__ __launch_bounds__(256) void maskpack_kernel(const int* __restrict__ attn,
                                                       const int* __restrict__ kv,
                                                       unsigned* __restrict__ out) {
  __shared__ int sflag;
  {
    unsigned v = ((const unsigned*)attn)[threadIdx.x];
    bool isbad = (v != 0u) && (v != 1u) && (v != 0x3f800000u);
    unsigned long long bal = __ballot(isbad);
    if (threadIdx.x == 0) sflag = 0;
    __syncthreads();
    if ((threadIdx.x & 63) == 0 && bal != 0ull) sflag = 1;
    __syncthreads();
  }
  const int flag = sflag;

  int idx = blockIdx.x * 256 + threadIdx.x;    // (b*kS + q)*64 + w
  int w = idx & 63;
  int q = (idx >> 6) & (kS - 1);
  int b = idx >> 17;
  unsigned m = 0;
  if (flag == 0) {
    const uint4* ap = (const uint4*)(attn + ((size_t)(b * kS + q)) * kS + w * 32);
    const uint4* kp = (const uint4*)(kv + b * kS + w * 32);
#pragma unroll
    for (int c = 0; c < 8; c++) {
      uint4 a = ap[c], k = kp[c];
      m |= ((unsigned)((a.x != 0u) & (k.x != 0u))) << (4 * c);
      m |= ((unsigned)((a.y != 0u) & (k.y != 0u))) << (4 * c + 1);
      m |= ((unsigned)((a.z != 0u) & (k.z != 0u))) << (4 * c + 2);
      m |= ((unsigned)((a.w != 0u) & (k.w != 0u))) << (4 * c + 3);
    }
  } else {
    const uint4* ap = (const uint4*)((const unsigned char*)attn + ((size_t)(b * kS + q)) * kS + w * 32);
    const uint4* kp = (const uint4*)((const unsigned char*)kv + b * kS + w * 32);
#pragma unroll
    for (int c = 0; c < 2; c++) {
      uint4 a = ap[c], k = kp[c];
      unsigned aw[4] = {a.x, a.y, a.z, a.w};
      unsigned kw[4] = {k.x, k.y, k.z, k.w};
#pragma unroll
      for (int d = 0; d < 4; d++)
#pragma unroll
        for (int j = 0; j < 4; j++) {
          unsigned ab = (aw[d] >> (8 * j)) & 0xffu;
          unsigned kb = (kw[d] >> (8 * j)) & 0xffu;
          m |= ((unsigned)((ab != 0u) & (kb != 0u))) << (16 * c + 4 * d + j);
        }
    }
  }
  out[idx] = m;
}

// ---------------- GEMM: C[M,N] = A[M,K] @ Bt[N,K]^T (+bias), bf16 in, f32 acc ----------------
// 128x128 tile, BK=64, 256 thr (4 waves, 2x2 of 64x64), 16x16x32 MFMA x2 k-halves.
// Swizzle: phys slot = logical ^ (row&7), via pre-swizzled global source.
// Linear x-major dim3 grid. (R12 lesson: co-resident set per XCD already fits L2 --
// temporal working set, not full-grid footprint, is what must fit; do not XCD-chunk.)
template <int OUT_BF16, int HAS_BIAS>
__global__ __launch_bounds__(256, 2) void gemm_kernel(const unsigned short* __restrict__ A,
                                                      const unsigned short* __restrict__ Bt,
                                                      void* __restrict__ Cv,
                                                      const float* __restrict__ bias,
                                                      int M, int N, int K) {
  __shared__ alignas(16) unsigned short As[128 * 64];
  __shared__ alignas(16) unsigned short Bs[128 * 64];
  const int tid  = threadIdx.x;
  const int lane = tid & 63;
  const int wave = tid >> 6;
  const int wr = wave >> 1, wc = wave & 1;
  const int bm = blockIdx.x * 128;
  const int bn = blockIdx.y * 128;

  f32x4 acc[4][4] = {};

  const int srow  = tid >> 3;                   // 0..31
  const int sslot = (tid & 7) ^ (srow & 7);
  const unsigned short* ga = A + (size_t)(bm + srow) * K + sslot * 8;
  const unsigned short* gb = Bt + (size_t)(bn + srow) * K + sslot * 8;
  char* lA = (char*)As + wave * 1024;           // linear dest: wave base + lane*16B
  char* lB = (char*)Bs + wave * 1024;

  for (int kk = 0; kk < K; kk += 64) {
    __syncthreads();
#pragma unroll
    for (int rb = 0; rb < 4; rb++) {
      gload_lds16(ga + (size_t)(32 * rb) * K, lA + rb * 4096);
      gload_lds16(gb + (size_t)(32 * rb) * K, lB + rb * 4096);
    }
    ga += 64; gb += 64;
    __syncthreads();

    bf16x8 af[4][2], bfr[4][2];
#pragma unroll
    for (int i = 0; i < 4; i++) {
#pragma unroll
      for (int t = 0; t < 2; t++) {
        int rA = wr * 64 + i * 16 + (lane & 15);
        int jA = (t * 4 + (lane >> 4)) ^ (rA & 7);
        af[i][t] = *(const bf16x8*)(As + rA * 64 + jA * 8);
        int rB = wc * 64 + i * 16 + (lane & 15);
        int jB = (t * 4 + (lane >> 4)) ^ (rB & 7);
        bfr[i][t] = *(const bf16x8*)(Bs + rB * 64 + jB * 8);
      }
    }
#pragma unroll
    for (int mi = 0; mi < 4; mi++)
#pragma unroll
      for (int ni = 0; ni < 4; ni++) {
        acc[mi][ni] = __builtin_amdgcn_mfma_f32_16x16x32_bf16(af[mi][0], bfr[ni][0], acc[mi][ni], 0, 0, 0);
        acc[mi][ni] = __builtin_amdgcn_mfma_f32_16x16x32_bf16(af[mi][1], bfr[ni][1], acc[mi][ni], 0, 0, 0);
      }
  }

  const int r0 = bm + wr * 64 + (lane >> 4) * 4;
  const int c0 = bn + wc * 64 + (lane & 15);
#pragma unroll
  for (int ni = 0; ni < 4; ni++) {
    int c = c0 + ni * 16;
    float bv = HAS_BIAS ? bias[c] : 0.0f;
#pragma unroll
    for (int mi = 0; mi < 4; mi++) {
#pragma unroll
      for (int j = 0; j < 4; j++) {
        int r = r0 + mi * 16 + j;
        float v = acc[mi][ni][j] + bv;
        if (OUT_BF16) ((unsigned short*)Cv)[(size_t)r * N + c] = f2bf(v);
        else          ((float*)Cv)[(size_t)r * N + c] = v;
      }
    }
  }
}

// ---------------- flash attention: R8 champion, verbatim ----------------
// software-pipelined, 512 thr, 1 barrier/tile. Grid (bh=32, qchunk=8): XCD = bh%8.
// Pipeline: QK^T(t+1) first; K(t+2) gload + V(t+2) loads before VALU phase; V write after PV.
// K double-buffered, V triple-buffered, scores ping-pong via 2x-unrolled body.
// ~164 unified regs/wave -> (512,2); >=4 waves/SIMD bounds spill catastrophically (R4/R6/R9).
__global__ __launch_bounds__(512, 2) void attn_kernel(const unsigned short* __restrict__ qkv,   // [4096][3072]
                                                      const unsigned* __restrict__ maskp,       // [B][S][64]
                                                      unsigned short* __restrict__ aout) {      // [4096][1024]
  __shared__ alignas(16) unsigned short Ks[2][64 * 64];   // [key][hd], 16B slot ^= key&7
  __shared__ alignas(16) unsigned short Vt[3][64 * 64];   // [hd][key], 16B slot ^= hd&7
  const int tid  = threadIdx.x;
  const int lane = tid & 63;
  const int wave = tid >> 6;
  const int half = lane >> 5;
  const int l31  = lane & 31;
  const int b = blockIdx.x >> 4;
  const int h = blockIdx.x & 15;
  const int qrow = blockIdx.y * 256 + wave * 32 + l31;
  const float NEGINF = -__builtin_inff();
  const float K2 = 1.4426950408889634f;     // log2(e)

  // Q fragments (B-operand), pre-scaled by 1/sqrt(HD)=0.125 (exact in bf16)
  bf16x8 qf[4];
  {
    const unsigned short* qp = qkv + (size_t)(b * kS + qrow) * kD3 + h * kHD + half * 8;
#pragma unroll
    for (int i = 0; i < 4; i++) {
      uint4 u = *(const uint4*)(qp + i * 16);
      unsigned w[4] = {u.x, u.y, u.z, u.w};
      union { unsigned u[4]; bf16x8 v; } o;
#pragma unroll
      for (int j = 0; j < 4; j++) {
        float lo = bf2f((unsigned short)(w[j] & 0xffffu)) * 0.125f;
        float hi = bf2f((unsigned short)(w[j] >> 16)) * 0.125f;
        o.u[j] = pk2(lo, hi);
      }
      qf[i] = o.v;
    }
  }

  f32x16 ot0 = {}, ot1 = {};                 // O^T acc: hd 0-31 / 32-63, col=qrow
  float mrun = NEGINF, lrun = 0.f, m2 = 0.f; // m2 = mrun*log2e
  const unsigned* mp = maskp + ((size_t)(b * kS) + qrow) * 64;

  // K staging: 16B chunk: row=tid>>3, dest slot=tid&7; source pre-swizzled
  const int krow  = tid >> 3;
  const int kslot = (tid & 7) ^ (krow & 7);
  const unsigned short* gk = qkv + (size_t)(b * kS + krow) * kD3 + kD + h * kHD + kslot * 8;

  // V staging (register transpose, b64 writes)
  const int vp = tid >> 4;          // hd pair {2vp, 2vp+1}
  const int vo = (tid >> 1) & 7;    // key octet
  const int vh = tid & 1;           // half-octet (4 keys)
  const unsigned short* gv = qkv + (size_t)(b * kS + 8 * vo + 4 * vh) * kD3 + 2 * kD + h * kHD + 2 * vp;
  const int vwo_lo = (2 * vp) * 128 + ((vo ^ ((2 * vp) & 7)) << 4) + vh * 8;           // bytes
  const int vwo_hi = (2 * vp + 1) * 128 + ((vo ^ ((2 * vp + 1) & 7)) << 4) + vh * 8;

  const size_t tstride = (size_t)64 * kD3;   // one 64-key tile

  // ---------------- prologue: stage K(0),K(1),V(0),V(1); QK^T(0) ----------------
  gload_lds16(gk, (char*)Ks[0] + tid * 16);
  gload_lds16(gk + tstride, (char*)Ks[1] + tid * 16);
  {
    unsigned p0 = *(const unsigned*)(gv);
    unsigned p1 = *(const unsigned*)(gv + kD3);
    unsigned p2 = *(const unsigned*)(gv + 2 * kD3);
    unsigned p3 = *(const unsigned*)(gv + 3 * kD3);
    char* vb = (char*)Vt[0];
    uint2 wlo, whi;
    wlo.x = __builtin_amdgcn_perm(p1, p0, 0x05040100u);
    wlo.y = __builtin_amdgcn_perm(p3, p2, 0x05040100u);
    whi.x = __builtin_amdgcn_perm(p1, p0, 0x07060302u);
    whi.y = __builtin_amdgcn_perm(p3, p2, 0x07060302u);
    *(uint2*)(vb + vwo_lo) = wlo;
    *(uint2*)(vb + vwo_hi) = whi;
  }
  unsigned v0 = *(const unsigned*)(gv + tstride);
  unsigned v1 = *(const unsigned*)(gv + tstride + kD3);
  unsigned v2 = *(const unsigned*)(gv + tstride + 2 * kD3);
  unsigned v3 = *(const unsigned*)(gv + tstride + 3 * kD3);
  uint2 mw = *(const uint2*)(mp);
  __syncthreads();                          // K0,K1 in LDS; V0 visible

  f32x16 sA0 = {}, sA1 = {}, sB0 = {}, sB1 = {};
  {
    const unsigned short* ksb = Ks[0];
    __builtin_amdgcn_s_setprio(1);
#pragma unroll
    for (int ii = 0; ii < 4; ii++) {
      int slot = (ii * 2 + half) ^ (l31 & 7);
      bf16x8 ka0 = *(const bf16x8*)(ksb + l31 * 64 + slot * 8);
      bf16x8 ka1 = *(const bf16x8*)(ksb + (l31 + 32) * 64 + slot * 8);
      sA0 = __builtin_amdgcn_mfma_f32_32x32x16_bf16(ka0, qf[ii], sA0, 0, 0, 0);
      sA1 = __builtin_amdgcn_mfma_f32_32x32x16_bf16(ka1, qf[ii], sA1, 0, 0, 0);
    }
    __builtin_amdgcn_s_setprio(0);
  }
  {
    char* vb = (char*)Vt[1];
    uint2 wlo, whi;
    wlo.x = __builtin_amdgcn_perm(v1, v0, 0x05040100u);
    wlo.y = __builtin_amdgcn_perm(v3, v2, 0x05040100u);
    whi.x = __builtin_amdgcn_perm(v1, v0, 0x07060302u);
    whi.y = __builtin_amdgcn_perm(v3, v2, 0x07060302u);
    *(uint2*)(vb + vwo_lo) = wlo;
    *(uint2*)(vb + vwo_hi) = whi;
  }
  __syncthreads();                          // QK^T(0) reads done (Ks[0] reusable); V1 visible

  int vrd_off = 0;                          // (t%3)*8192 bytes
  int vwr_off = 16384;                      // ((t+2)%3)*8192 bytes

  // body(t): QK^T(t+1)->NXT from KNXT; gload K(t+2)->KDST; softmax+PV(t) on CUR
#define BODY(T, CUR0, CUR1, NXT0, NXT1, KNXT, KDST)                                         \
  {                                                                                         \
    const int t_ = (T);                                                                     \
    if (t_ < 31) {                                                                          \
      const unsigned short* ksb = (KNXT);                                                   \
      NXT0 = (f32x16){}; NXT1 = (f32x16){};                                                 \
      __builtin_amdgcn_s_setprio(1);                                                        \
      _Pragma("unroll")                                                                     \
      for (int ii = 0; ii < 4; ii++) {                                                      \
        int slot = (ii * 2 + half) ^ (l31 & 7);                                             \
        bf16x8 ka0 = *(const bf16x8*)(ksb + l31 * 64 + slot * 8);                           \
        bf16x8 ka1 = *(const bf16x8*)(ksb + (l31 + 32) * 64 + slot * 8);                    \
        NXT0 = __builtin_amdgcn_mfma_f32_32x32x16_bf16(ka0, qf[ii], NXT0, 0, 0, 0);         \
        NXT1 = __builtin_amdgcn_mfma_f32_32x32x16_bf16(ka1, qf[ii], NXT1, 0, 0, 0);         \
      }                                                                                     \
      __builtin_amdgcn_s_setprio(0);                                                        \
    }                                                                                       \
    __builtin_amdgcn_sched_barrier(0);                                                      \
    uint2 mwn = mw;                                                                         \
    if (t_ < 31) mwn = *(const uint2*)(mp + 2 * (t_ + 1));                                  \
    if (t_ < 30) {                                                                          \
      gload_lds16(gk + (size_t)(t_ + 2) * tstride, (KDST) + tid * 16);                      \
      const unsigned short* gvn = gv + (size_t)(t_ + 2) * tstride;                          \
      v0 = *(const unsigned*)(gvn);                                                         \
      v1 = *(const unsigned*)(gvn + kD3);                                                   \
      v2 = *(const unsigned*)(gvn + 2 * kD3);                                               \
      v3 = *(const unsigned*)(gvn + 3 * kD3);                                               \
    }                                                                                       \
    const unsigned mx = mw.x >> (4 * half);                                                 \
    const unsigned my = mw.y >> (4 * half);                                                 \
    float pm = NEGINF;                                                                      \
    _Pragma("unroll")                                                                       \
    for (int r = 0; r < 16; r++) pm = max3f(CUR0[r], CUR1[r], pm);                          \
    pm = fmaxf(pm, __shfl_xor(pm, 32));                                                     \
    if (__any(pm > mrun + 8.0f)) {                                                          \
      float mn = fmaxf(mrun, pm);                                                           \
      float m2n = mn * K2;                                                                  \
      float sc = __builtin_amdgcn_exp2f(fmaf(mrun, K2, -m2n));                              \
      m2 = m2n; mrun = mn; lrun *= sc;                                                      \
      _Pragma("unroll")                                                                     \
      for (int r = 0; r < 16; r++) { ot0[r] *= sc; ot1[r] *= sc; }                          \
    }                                                                                       \
    float ls0 = 0.f, ls1 = 0.f;                                                             \
    _Pragma("unroll")                                                                       \
    for (int r = 0; r < 16; r++) {                                                          \
      const int kb = (r & 3) + 8 * (r >> 2);                                                \
      float p0 = __builtin_amdgcn_exp2f(fmaf(CUR0[r], K2, -m2));                            \
      float p1 = __builtin_amdgcn_exp2f(fmaf(CUR1[r], K2, -m2));                            \
      unsigned z0 = (unsigned)__builtin_amdgcn_sbfe(mx, kb, 1);                             \
      unsigned z1 = (unsigned)__builtin_amdgcn_sbfe(my, kb, 1);                             \
      p0 = __uint_as_float(__float_as_uint(p0) & z0);                                       \
      p1 = __uint_as_float(__float_as_uint(p1) & z1);                                       \
      CUR0[r] = p0; CUR1[r] = p1;                                                           \
      ls0 += p0; ls1 += p1;                                                                 \
    }                                                                                       \
    float ls = ls0 + ls1;                                                                   \
    ls += __shfl_xor(ls, 32);                                                               \
    lrun += ls;                                                                             \
    const char* vtb = (const char*)Vt[0] + vrd_off;                                         \
    _Pragma("unroll")                                                                       \
    for (int gg = 0; gg < 2; gg++) {                                                        \
      unsigned w8[8];                                                                       \
      _Pragma("unroll")                                                                     \
      for (int j = 0; j < 8; j++)                                                           \
        w8[j] = gg ? cvtpk(CUR1[2 * j], CUR1[2 * j + 1])                                    \
                   : cvtpk(CUR0[2 * j], CUR0[2 * j + 1]);                                   \
      _Pragma("unroll")                                                                     \
      for (int cc = 0; cc < 2; cc++) {                                                      \
        unsigned u0 = w8[4 * cc],     u2 = w8[4 * cc + 2];                                  \
        unsigned u1 = w8[4 * cc + 1], u3 = w8[4 * cc + 3];                                  \
        asm("v_permlane32_swap_b32 %0, %1" : "+v"(u0), "+v"(u2));                           \
        asm("v_permlane32_swap_b32 %0, %1" : "+v"(u1), "+v"(u3));                           \
        union { unsigned u[4]; bf16x8 v; } pb;                                              \
        pb.u[0] = u0; pb.u[1] = u1; pb.u[2] = u2; pb.u[3] = u3;                             \
        int c = gg * 2 + cc;                                                                \
        int kslotc = (c * 2 + half) ^ (l31 & 7);                                            \
        __builtin_amdgcn_s_setprio(1);                                                      \
        {                                                                                   \
          bf16x8 va0 = *(const bf16x8*)(vtb + l31 * 128 + kslotc * 16);                     \
          bf16x8 va1 = *(const bf16x8*)(vtb + (l31 + 32) * 128 + kslotc * 16);              \
          ot0 = __builtin_amdgcn_mfma_f32_32x32x16_bf16(va0, pb.v, ot0, 0, 0, 0);           \
          ot1 = __builtin_amdgcn_mfma_f32_32x32x16_bf16(va1, pb.v, ot1, 0, 0, 0);           \
        }                                                                                   \
        __builtin_amdgcn_s_setprio(0);                                                      \
      }                                                                                     \
    }                                                                                       \
    if (t_ < 30) {                                                                          \
      char* vb = (char*)Vt[0] + vwr_off;                                                    \
      uint2 wlo, whi;                                                                       \
      wlo.x = __builtin_amdgcn_perm(v1, v0, 0x05040100u);                                   \
      wlo.y = __builtin_amdgcn_perm(v3, v2, 0x05040100u);                                   \
      whi.x = __builtin_amdgcn_perm(v1, v0, 0x07060302u);                                   \
      whi.y = __builtin_amdgcn_perm(v3, v2, 0x07060302u);                                   \
      *(uint2*)(vb + vwo_lo) = wlo;                                                         \
      *(uint2*)(vb + vwo_hi) = whi;                                                         \
    }                                                                                       \
    mw = mwn;                                                                               \
    vrd_off = (vrd_off == 16384) ? 0 : vrd_off + 8192;                                      \
    vwr_off = (vwr_off == 16384) ? 0 : vwr_off + 8192;                                      \
    __syncthreads();                                                                        \
  }

  for (int tp = 0; tp < 16; ++tp) {
    const int te = 2 * tp;
    BODY(te,     sA0, sA1, sB0, sB1, Ks[1], (char*)Ks[0]);
    BODY(te + 1, sB0, sB1, sA0, sA1, Ks[0], (char*)Ks[1]);
  }
#undef BODY

  // ---- normalize + write a_out bf16 (fully-masked row -> 0) ----
  float rl = (lrun > 0.f) ? (1.f / lrun) : 0.f;
  unsigned short* op = aout + (size_t)(b * kS + qrow) * kD + h * kHD;
#pragma unroll
  for (int hh = 0; hh < 2; hh++) {
#pragma unroll
    for (int qd = 0; qd < 4; qd++) {
      float x0 = (hh ? ot1[4 * qd]     : ot0[4 * qd])     * rl;
      float x1 = (hh ? ot1[4 * qd + 1] : ot0[4 * qd + 1]) * rl;
      float x2 = (hh ? ot1[4 * qd + 2] : ot0[4 * qd + 2]) * rl;
      float x3 = (hh ? ot1[4 * qd + 3] : ot0[4 * qd + 3]) * rl;
      uint2 o;
      o.x = pk2(x0, x1);
      o.y = pk2(x2, x3);
      *(uint2*)(op + hh * 32 + qd * 8 + half * 4) = o;
    }
  }
}

}  // namespace

extern "C" void kernel_launch(void* const* d_in, const int* in_sizes, int n_in,
                              void* d_out, int out_size, void* d_ws, size_t ws_size,
                              hipStream_t stream) {
  (void)in_sizes; (void)n_in; (void)out_size; (void)ws_size;
  const float* q     = (const float*)d_in[0];
  const int*   kvm   = (const int*)d_in[1];
  const int*   am    = (const int*)d_in[2];
  const float* W_all = (const float*)d_in[3];
  const float* W_out = (const float*)d_in[4];
  const float* b_out = (const float*)d_in[5];

  char* ws = (char*)d_ws;
  unsigned short* qkv  = (unsigned short*)(ws);                    // 25,165,824 B
  unsigned short* qbf  = (unsigned short*)(ws + 25165824);         //  8,388,608 B (reused as aout)
  unsigned short* aout = qbf;
  unsigned short* wabf = (unsigned short*)(ws + 33554432);         //  6,291,456 B
  unsigned short* wobf = (unsigned short*)(ws + 39845888);         //  2,097,152 B
  unsigned*       mskp = (unsigned*)(ws + 41943040);               //  1,048,576 B

  prep_kernel<<<8192, 256, 0, stream>>>(q, W_all, W_out, qbf, wabf, wobf);
  maskpack_kernel<<<1024, 256, 0, stream>>>(am, kvm, mskp);
  // qkv[4096,3072] = q_bf @ W_all^T ; linear x-major grid (co-resident set fits L2)
  gemm_kernel<1, 0><<<dim3(kBS / 128, kD3 / 128), 256, 0, stream>>>(qbf, wabf, qkv, nullptr, kBS, kD3, kD);
  // a_out[4096,1024] (bf16); grid x=bh (XCD-local K/V), y=q-chunk
  attn_kernel<<<dim3(kB * kH, kS / 256), 512, 0, stream>>>(qkv, mskp, aout);
  // out[4096,1024] = a_out @ W_out^T + b_out (f32)
  gemm_kernel<0, 1><<<dim3(kBS / 128, kD / 128), 256, 0, stream>>>(aout, wobf, d_out, b_out, kBS, kD, kD);
}